// Round 19
// baseline (214.829 us; speedup 1.0000x reference)
//
#include <hip/hip_runtime.h>

// HyperMixer fused kernel, MI355X (gfx950) — round 19.
// x[8192,4,2048] f32, out[8192,2048] f32, W[24][8192] f32 -> y + collapsed.
//
// r10-r18: ten variants plateau 175-240us. Additive accounting closes:
// HBM ~90 + VALU ~40 + W-L2 ~30 + LDS ~30 + serial ~5 ~= measured ->
// phases have near-zero overlap; cross-block stagger never materializes
// (r12 null); allocator vetoes big register pipelines (52-VGPR pin,
// r13/r14/r17). THIS round: intra-block self-overlap with a TINY live
// set. 512 blocks (exactly 2/CU, resident whole kernel), each owns 16
// tokens = 8 groups of 2. Phase A(g)'s 16-iter dot loop is ALSO the
// producer for group g+1: one float4 x-load per 2 iters, packed+ds_
// written one pair later (named vP/vN regs only - 8 VGPR, under the cap;
// no runtime-indexed array -> no scratch). LDS: dbuf f16 xh = 64 KB ->
// 2 blocks/CU. 3 barriers/group (3rd protects xh[cur] from the next
// producer). Sumsq in the producer (exact f32).
// Kept proven: linear f16 W + v_dot2_f32_f16, scalar 2-lane sinkhorn
// (r13), phase-B from f16 LDS (absmax 0.03125), bare __launch_bounds__.
// Tripwire: WRITE_SIZE == 327,680 KB exactly (no spill).

#define EPS 1e-6f
constexpr int D_ = 2048, KD = 8192, NOUT = 24;
constexpr int NTOK = 8192;
constexpr int TPB = 512;
constexpr int TPG = 2;                       // tokens per group
constexpr int GRP = 8;                       // groups per block
constexpr int NBLK = NTOK / (TPG * GRP);     // 512 = 2 blocks/CU resident

typedef _Float16 h2 __attribute__((ext_vector_type(2)));

static __device__ __forceinline__ unsigned int pk2(float a, float b) {
#if __has_builtin(__builtin_amdgcn_cvt_pkrtz)
    auto r = __builtin_amdgcn_cvt_pkrtz(a, b);
    return __builtin_bit_cast(unsigned int, r);
#else
    h2 h; h.x = (_Float16)a; h.y = (_Float16)b;
    return __builtin_bit_cast(unsigned int, h);
#endif
}

static __device__ __forceinline__ float dot2(unsigned int w, unsigned int x, float c) {
#if __has_builtin(__builtin_amdgcn_fdot2)
    return __builtin_amdgcn_fdot2(__builtin_bit_cast(h2, w),
                                  __builtin_bit_cast(h2, x), c, false);
#else
    h2 hw = __builtin_bit_cast(h2, w), hx = __builtin_bit_cast(h2, x);
    return c + (float)hw.x * (float)hx.x + (float)hw.y * (float)hx.y;
#endif
}

static __device__ __forceinline__ float frcp(float v) {
#if __has_builtin(__builtin_amdgcn_rcpf)
    return __builtin_amdgcn_rcpf(v);
#else
    return 1.f / v;
#endif
}

// Wh: LINEAR f16 of W. Thread g converts 8 consecutive floats.
__global__ void conv_w_kernel(const float* __restrict__ W, unsigned int* __restrict__ Wh) {
    int g = blockIdx.x * blockDim.x + threadIdx.x;   // 24576 threads
    const float* src = W + (size_t)g * 8;
    float4 a = *reinterpret_cast<const float4*>(src);
    float4 b = *reinterpret_cast<const float4*>(src + 4);
    uint4 u;
    u.x = pk2(a.x, a.y); u.y = pk2(a.z, a.w);
    u.z = pk2(b.x, b.y); u.w = pk2(b.z, b.w);
    *reinterpret_cast<uint4*>(Wh + (size_t)g * 4) = u;
}

__global__ __launch_bounds__(TPB) void hypermix_kernel(
    const float* __restrict__ x, const float* __restrict__ outp,
    const unsigned int* __restrict__ Wh,
    const float* __restrict__ scale, const float* __restrict__ base,
    float* __restrict__ y, float* __restrict__ coll)
{
    const int t = threadIdx.x;
    const int w = t >> 6, lane = t & 63;
    const size_t tok0 = (size_t)blockIdx.x * (TPG * GRP);

    __shared__ unsigned int xh[2][TPG][KD / 2];  // f16 dbuf, 64 KB
    __shared__ float ssred[2][8][TPG];           // per-wave sumsq partials
    __shared__ float lg[TPG][NOUT];              // raw dots (single buffer ok)
    __shared__ float wts[TPG][NOUT];             // weights (single buffer ok)

    // ---- prologue: stage group 0 (load -> pack f16 -> LDS, sumsq) ----
    {
        float ssA = 0.f, ssB = 0.f;
#pragma unroll 2
        for (int s = 0; s < 8; ++s) {
            const int tl = s >> 2, c = s & 3;
            float4 v = *reinterpret_cast<const float4*>(
                x + (tok0 + tl) * KD + c * 2048 + t * 4);
            float sq = v.x * v.x + v.y * v.y + v.z * v.z + v.w * v.w;
            if (tl == 0) ssA += sq; else ssB += sq;
            uint2 p; p.x = pk2(v.x, v.y); p.y = pk2(v.z, v.w);
            *reinterpret_cast<uint2*>(&xh[0][tl][c * 1024 + t * 2]) = p;
        }
#pragma unroll
        for (int m = 1; m < 64; m <<= 1) {
            ssA += __shfl_xor(ssA, m, 64);
            ssB += __shfl_xor(ssB, m, 64);
        }
        if (lane == 0) { ssred[0][w][0] = ssA; ssred[0][w][1] = ssB; }
    }
    __syncthreads();

    // ---- strip loop over 8 groups ----
#pragma unroll 1
    for (int g = 0; g < GRP; ++g) {
        const int cur = g & 1, nxt = cur ^ 1;
        const size_t gt = tok0 + (size_t)g * TPG;
        const bool prod = (g + 1 < GRP);
        const size_t ntk = gt + TPG;           // first token of next group
        const int r0 = w * 3;

        // phase A(g) fused with producer(g+1)
        {
            float a00 = 0.f, a01 = 0.f, a10 = 0.f, a11 = 0.f, a20 = 0.f, a21 = 0.f;
            float ssA = 0.f, ssB = 0.f;
            float4 vP, vN;

#define CONSUME_IT(IT) do {                                                  \
            const int gi4 = ((IT) * 64 + lane) * 4;                          \
            uint4 xa = *reinterpret_cast<const uint4*>(&xh[cur][0][gi4]);    \
            uint4 xb = *reinterpret_cast<const uint4*>(&xh[cur][1][gi4]);    \
            uint4 w0 = *reinterpret_cast<const uint4*>(Wh + (size_t)(r0 + 0) * 4096 + gi4); \
            uint4 w1 = *reinterpret_cast<const uint4*>(Wh + (size_t)(r0 + 1) * 4096 + gi4); \
            uint4 w2 = *reinterpret_cast<const uint4*>(Wh + (size_t)(r0 + 2) * 4096 + gi4); \
            a00 = dot2(w0.x, xa.x, a00); a00 = dot2(w0.y, xa.y, a00);        \
            a00 = dot2(w0.z, xa.z, a00); a00 = dot2(w0.w, xa.w, a00);        \
            a01 = dot2(w0.x, xb.x, a01); a01 = dot2(w0.y, xb.y, a01);        \
            a01 = dot2(w0.z, xb.z, a01); a01 = dot2(w0.w, xb.w, a01);        \
            a10 = dot2(w1.x, xa.x, a10); a10 = dot2(w1.y, xa.y, a10);        \
            a10 = dot2(w1.z, xa.z, a10); a10 = dot2(w1.w, xa.w, a10);        \
            a11 = dot2(w1.x, xb.x, a11); a11 = dot2(w1.y, xb.y, a11);        \
            a11 = dot2(w1.z, xb.z, a11); a11 = dot2(w1.w, xb.w, a11);        \
            a20 = dot2(w2.x, xa.x, a20); a20 = dot2(w2.y, xa.y, a20);        \
            a20 = dot2(w2.z, xa.z, a20); a20 = dot2(w2.w, xa.w, a20);        \
            a21 = dot2(w2.x, xb.x, a21); a21 = dot2(w2.y, xb.y, a21);        \
            a21 = dot2(w2.z, xb.z, a21); a21 = dot2(w2.w, xb.w, a21);        \
        } while (0)

#define DRAIN(S, V) do {                                                     \
            const int tl = (S) >> 2, c = (S) & 3;                            \
            float sq = V.x * V.x + V.y * V.y + V.z * V.z + V.w * V.w;        \
            if (tl == 0) ssA += sq; else ssB += sq;                          \
            uint2 p; p.x = pk2(V.x, V.y); p.y = pk2(V.z, V.w);               \
            *reinterpret_cast<uint2*>(&xh[nxt][tl][c * 1024 + t * 2]) = p;   \
        } while (0)

            // software pipeline: load chunk s at pair s, drain at pair s+1
#pragma unroll 1
            for (int s = 0; s < 8; ++s) {
                if (prod) vN = *reinterpret_cast<const float4*>(
                    x + (ntk + (s >> 2)) * KD + (s & 3) * 2048 + t * 4);
                CONSUME_IT(2 * s);
                CONSUME_IT(2 * s + 1);
                if (prod && s > 0) DRAIN(s - 1, vP);
                vP = vN;
            }
            if (prod) DRAIN(7, vP);
#undef CONSUME_IT
#undef DRAIN

            // interleaved butterfly reduces
#pragma unroll
            for (int m = 1; m < 64; m <<= 1) {
                a00 += __shfl_xor(a00, m, 64); a01 += __shfl_xor(a01, m, 64);
                a10 += __shfl_xor(a10, m, 64); a11 += __shfl_xor(a11, m, 64);
                a20 += __shfl_xor(a20, m, 64); a21 += __shfl_xor(a21, m, 64);
            }
            if (lane == 0) {
                lg[0][r0] = a00;     lg[1][r0] = a01;
                lg[0][r0 + 1] = a10; lg[1][r0 + 1] = a11;
                lg[0][r0 + 2] = a20; lg[1][r0 + 2] = a21;
            }
            if (prod) {
#pragma unroll
                for (int m = 1; m < 64; m <<= 1) {
                    ssA += __shfl_xor(ssA, m, 64);
                    ssB += __shfl_xor(ssB, m, 64);
                }
                if (lane == 0) { ssred[nxt][w][0] = ssA; ssred[nxt][w][1] = ssB; }
            }
        }
        __syncthreads();   // barrier 1: lg/ssred visible

        // out prefetch (covered by weights) + scalar weights on 2 lanes
        float4 ov0 = *reinterpret_cast<const float4*>(outp + gt * D_ + t * 4);
        float4 ov1 = *reinterpret_cast<const float4*>(outp + (gt + 1) * D_ + t * 4);
        if (t < TPG) {
            float ss = 0.f;
#pragma unroll
            for (int i = 0; i < 8; ++i) ss += ssred[cur][i][t];
            float rms = rsqrtf(ss * (1.f / 8192.f) + EPS);
            float s0 = scale[0], s1 = scale[1], s2 = scale[2];
            float l[24];
#pragma unroll
            for (int i = 0; i < 24; ++i) l[i] = lg[t][i];
#pragma unroll
            for (int k = 0; k < 4; ++k) {
                float z0 = l[k] * rms * s0 + base[k];
                wts[t][k] = frcp(1.f + __expf(-z0)) + EPS;
                float z1 = l[4 + k] * rms * s1 + base[4 + k];
                wts[t][4 + k] = 2.f * frcp(1.f + __expf(-z1));
            }
            float p[16];
#pragma unroll
            for (int h = 0; h < 4; ++h) {
                float c0 = l[8 + h * 4 + 0] * rms * s2 + base[8 + h * 4 + 0];
                float c1 = l[8 + h * 4 + 1] * rms * s2 + base[8 + h * 4 + 1];
                float c2 = l[8 + h * 4 + 2] * rms * s2 + base[8 + h * 4 + 2];
                float c3 = l[8 + h * 4 + 3] * rms * s2 + base[8 + h * 4 + 3];
                float mx = fmaxf(fmaxf(c0, c1), fmaxf(c2, c3));
                float e0 = __expf(c0 - mx), e1 = __expf(c1 - mx);
                float e2 = __expf(c2 - mx), e3 = __expf(c3 - mx);
                float inv = frcp(e0 + e1 + e2 + e3);
                p[h * 4 + 0] = e0 * inv + EPS; p[h * 4 + 1] = e1 * inv + EPS;
                p[h * 4 + 2] = e2 * inv + EPS; p[h * 4 + 3] = e3 * inv + EPS;
            }
#pragma unroll
            for (int k = 0; k < 4; ++k) {
                float inv = frcp(p[k] + p[4 + k] + p[8 + k] + p[12 + k] + EPS);
                p[k] *= inv; p[4 + k] *= inv; p[8 + k] *= inv; p[12 + k] *= inv;
            }
#pragma unroll 1
            for (int itn = 0; itn < 19; ++itn) {
#pragma unroll
                for (int h = 0; h < 4; ++h) {
                    float inv = frcp(p[h * 4] + p[h * 4 + 1] + p[h * 4 + 2] + p[h * 4 + 3] + EPS);
                    p[h * 4] *= inv; p[h * 4 + 1] *= inv; p[h * 4 + 2] *= inv; p[h * 4 + 3] *= inv;
                }
#pragma unroll
                for (int k = 0; k < 4; ++k) {
                    float inv = frcp(p[k] + p[4 + k] + p[8 + k] + p[12 + k] + EPS);
                    p[k] *= inv; p[4 + k] *= inv; p[8 + k] *= inv; p[12 + k] *= inv;
                }
            }
#pragma unroll
            for (int i = 0; i < 16; ++i) wts[t][8 + i] = p[i];
        }
        __syncthreads();   // barrier 2: wts ready

        // phase B: both tokens from f16 LDS; out already in regs
#pragma unroll
        for (int tt = 0; tt < TPG; ++tt) {
            float pre[4], post[4], cmb[4][4];
#pragma unroll
            for (int k = 0; k < 4; ++k) { pre[k] = wts[tt][k]; post[k] = wts[tt][4 + k]; }
#pragma unroll
            for (int h = 0; h < 4; ++h)
#pragma unroll
                for (int k = 0; k < 4; ++k) cmb[h][k] = wts[tt][8 + h * 4 + k];

            const int d = t * 4;
            float xk[4][4];
#pragma unroll
            for (int k = 0; k < 4; ++k) {
                uint2 pq = *reinterpret_cast<const uint2*>(&xh[cur][tt][k * 1024 + t * 2]);
                h2 h0 = __builtin_bit_cast(h2, pq.x), h1 = __builtin_bit_cast(h2, pq.y);
                xk[k][0] = (float)h0.x; xk[k][1] = (float)h0.y;
                xk[k][2] = (float)h1.x; xk[k][3] = (float)h1.y;
            }
            float4 ov = tt ? ov1 : ov0;
            const float oe[4] = {ov.x, ov.y, ov.z, ov.w};
            float* yb = y + (gt + tt) * KD;
            float* cb = coll + (gt + tt) * D_;
            float cv[4], yv[4];
#pragma unroll
            for (int e = 0; e < 4; ++e)
                cv[e] = pre[0] * xk[0][e] + pre[1] * xk[1][e]
                      + pre[2] * xk[2][e] + pre[3] * xk[3][e];
            *reinterpret_cast<float4*>(cb + d) = make_float4(cv[0], cv[1], cv[2], cv[3]);
#pragma unroll
            for (int h = 0; h < 4; ++h) {
#pragma unroll
                for (int e = 0; e < 4; ++e)
                    yv[e] = post[h] * oe[e] + cmb[h][0] * xk[0][e] + cmb[h][1] * xk[1][e]
                          + cmb[h][2] * xk[2][e] + cmb[h][3] * xk[3][e];
                *reinterpret_cast<float4*>(yb + h * D_ + d) =
                    make_float4(yv[0], yv[1], yv[2], yv[3]);
            }
        }
        __syncthreads();   // barrier 3: xh[cur] free for next producer
    }
}

extern "C" void kernel_launch(void* const* d_in, const int* in_sizes, int n_in,
                              void* d_out, int out_size, void* d_ws, size_t ws_size,
                              hipStream_t stream) {
    const float* x     = (const float*)d_in[0];
    const float* outp  = (const float*)d_in[1];
    const float* W     = (const float*)d_in[2];
    const float* scale = (const float*)d_in[3];
    const float* base  = (const float*)d_in[4];
    float* y    = (float*)d_out;
    float* coll = y + (size_t)NTOK * KD;   // 67108864

    unsigned int* Wh = (unsigned int*)d_ws;     // 384 KB f16 (ws is larger)
    conv_w_kernel<<<NOUT * KD / 8 / 256, 256, 0, stream>>>(W, Wh);
    hypermix_kernel<<<NBLK, TPB, 0, stream>>>(x, outp, Wh, scale, base, y, coll);
}

// Round 20
// 176.802 us; speedup vs baseline: 1.2151x; 1.2151x over previous
//
#include <hip/hip_runtime.h>

// HyperMixer fused kernel, MI355X (gfx950) — round 20.
// x[8192,4,2048] f32, out[8192,2048] f32, W[24][8192] f32 -> y + collapsed.
//
// = round-13 (best, 175.5us) + sched_group_barrier pins (T19).
// Plateau theory (r10-r19, 12 variants, 175-240us): dual latency-crawl.
// The scheduler sinks loads next to uses (live-range minimization, lands
// at 52 VGPR regardless of launch_bounds), leaving ~2 x-loads and ~6
// W-loads in flight per wave -> x streams at ~1/3 HBM BW, W at ~20 GB/s
// per CU from L2. r13's source-level 2-stage pipeline was collapsed by
// the scheduler (VGPR 52 = r12, null result). SGB pins forbid the
// collapse: phase 0 pins all 15 VMEM reads first; phase A pins per-iter
// [3 VMEM][3 DS][3 VMEM][3 DS][VALU] so iter i's loads issue before
// iter i-1's dot2s consume (2x MLP on both streams).
// Diagnostic: VGPR 64-100 = pin took effect; VGPR 52 = hipcc collapsed
// the groups -> toolchain wall, declare plateau.
// Kept verbatim from r13: TOKS=3, f16 W conv pre-pass + v_dot2_f32_f16,
// scalar 3-lane in-reg sinkhorn, full-issue phase 0 with out-prefetch,
// bare __launch_bounds__. Tripwire: WRITE_SIZE == 327,680 KB (no spill).

#define EPS 1e-6f
constexpr int D_ = 2048, KD = 8192, NOUT = 24;
constexpr int NTOK = 8192;
constexpr int TPB = 512;
constexpr int TOKS = 3;
constexpr int NBLK = (NTOK + TOKS - 1) / TOKS;   // 2731

typedef _Float16 h2 __attribute__((ext_vector_type(2)));

static __device__ __forceinline__ unsigned int pk2(float a, float b) {
#if __has_builtin(__builtin_amdgcn_cvt_pkrtz)
    auto r = __builtin_amdgcn_cvt_pkrtz(a, b);
    return __builtin_bit_cast(unsigned int, r);
#else
    h2 h; h.x = (_Float16)a; h.y = (_Float16)b;
    return __builtin_bit_cast(unsigned int, h);
#endif
}

static __device__ __forceinline__ float dot2(unsigned int w, unsigned int x, float c) {
#if __has_builtin(__builtin_amdgcn_fdot2)
    return __builtin_amdgcn_fdot2(__builtin_bit_cast(h2, w),
                                  __builtin_bit_cast(h2, x), c, false);
#else
    h2 hw = __builtin_bit_cast(h2, w), hx = __builtin_bit_cast(h2, x);
    return c + (float)hw.x * (float)hx.x + (float)hw.y * (float)hx.y;
#endif
}

static __device__ __forceinline__ float frcp(float v) {
#if __has_builtin(__builtin_amdgcn_rcpf)
    return __builtin_amdgcn_rcpf(v);
#else
    return 1.f / v;
#endif
}

// sched_group_barrier masks (LLVM SchedGroupMask)
#define SGB(mask, n) __builtin_amdgcn_sched_group_barrier((mask), (n), 0)
#define M_VALU   0x2
#define M_VMEMRD 0x20
#define M_DSRD   0x100

// Wh: linear f16 of W. Thread g converts 8 consecutive floats.
__global__ void conv_w_kernel(const float* __restrict__ W, unsigned int* __restrict__ Wh) {
    int g = blockIdx.x * blockDim.x + threadIdx.x;   // 24576 threads
    const float* src = W + (size_t)g * 8;
    float4 a = *reinterpret_cast<const float4*>(src);
    float4 b = *reinterpret_cast<const float4*>(src + 4);
    uint4 u;
    u.x = pk2(a.x, a.y); u.y = pk2(a.z, a.w);
    u.z = pk2(b.x, b.y); u.w = pk2(b.z, b.w);
    *reinterpret_cast<uint4*>(Wh + (size_t)g * 4) = u;
}

__global__ __launch_bounds__(TPB) void hypermix_kernel(
    const float* __restrict__ x, const float* __restrict__ outp,
    const unsigned int* __restrict__ Wh,
    const float* __restrict__ scale, const float* __restrict__ base,
    float* __restrict__ y, float* __restrict__ coll)
{
    const int t = threadIdx.x;
    const int w = t >> 6, lane = t & 63;
    const size_t gt0 = (size_t)blockIdx.x * TOKS;
    const size_t tk0 = gt0;
    const size_t tk1 = (gt0 + 1 < NTOK) ? gt0 + 1 : NTOK - 1;
    const size_t tk2 = (gt0 + 2 < NTOK) ? gt0 + 2 : NTOK - 1;

    __shared__ unsigned int xh[TOKS][KD / 2];  // packed f16 x, 48 KB
    __shared__ float ssred[TOKS][8];           // per-wave sumsq partials
    __shared__ float lg[TOKS][24];             // raw dot products
    __shared__ float wts[TOKS][24];            // 0..3 pre, 4..7 post, 8..23 comb

    // ---- phase 0: issue ALL 15 loads (12 x + 3 out) first [SGB-pinned] ----
    float4 ov0, ov1, ov2;
    {
        const float* xb0 = x + tk0 * KD + t * 4;
        const float* xb1 = x + tk1 * KD + t * 4;
        const float* xb2 = x + tk2 * KD + t * 4;
        float4 a0[4], a1[4], a2[4];
#pragma unroll
        for (int i = 0; i < 4; ++i) a0[i] = *reinterpret_cast<const float4*>(xb0 + i * 2048);
#pragma unroll
        for (int i = 0; i < 4; ++i) a1[i] = *reinterpret_cast<const float4*>(xb1 + i * 2048);
#pragma unroll
        for (int i = 0; i < 4; ++i) a2[i] = *reinterpret_cast<const float4*>(xb2 + i * 2048);
        ov0 = *reinterpret_cast<const float4*>(outp + tk0 * D_ + t * 4);
        ov1 = *reinterpret_cast<const float4*>(outp + tk1 * D_ + t * 4);
        ov2 = *reinterpret_cast<const float4*>(outp + tk2 * D_ + t * 4);

        float ss0 = 0.f, ss1 = 0.f, ss2 = 0.f;
#pragma unroll
        for (int i = 0; i < 4; ++i) {
            ss0 += a0[i].x * a0[i].x + a0[i].y * a0[i].y + a0[i].z * a0[i].z + a0[i].w * a0[i].w;
            uint2 p0; p0.x = pk2(a0[i].x, a0[i].y); p0.y = pk2(a0[i].z, a0[i].w);
            *reinterpret_cast<uint2*>(&xh[0][i * 1024 + t * 2]) = p0;
            ss1 += a1[i].x * a1[i].x + a1[i].y * a1[i].y + a1[i].z * a1[i].z + a1[i].w * a1[i].w;
            uint2 p1; p1.x = pk2(a1[i].x, a1[i].y); p1.y = pk2(a1[i].z, a1[i].w);
            *reinterpret_cast<uint2*>(&xh[1][i * 1024 + t * 2]) = p1;
            ss2 += a2[i].x * a2[i].x + a2[i].y * a2[i].y + a2[i].z * a2[i].z + a2[i].w * a2[i].w;
            uint2 p2; p2.x = pk2(a2[i].x, a2[i].y); p2.y = pk2(a2[i].z, a2[i].w);
            *reinterpret_cast<uint2*>(&xh[2][i * 1024 + t * 2]) = p2;
        }
        // pin: all 15 VMEM reads issue before everything else
        SGB(M_VMEMRD, 15);

#pragma unroll
        for (int m = 1; m < 64; m <<= 1) {
            ss0 += __shfl_xor(ss0, m, 64);
            ss1 += __shfl_xor(ss1, m, 64);
            ss2 += __shfl_xor(ss2, m, 64);
        }
        if (lane == 0) { ssred[0][w] = ss0; ssred[1][w] = ss1; ssred[2][w] = ss2; }
    }
    __syncthreads();

    // ---- phase A: wave w -> rows 3w..3w+2, 2-stage pipeline [SGB-pinned] ----
    {
        const int r0 = w * 3;
        const unsigned int* Wp0 = Wh + (size_t)(r0 + 0) * 4096;
        const unsigned int* Wp1 = Wh + (size_t)(r0 + 1) * 4096;
        const unsigned int* Wp2 = Wh + (size_t)(r0 + 2) * 4096;
        float a00 = 0.f, a01 = 0.f, a02 = 0.f;
        float a10 = 0.f, a11 = 0.f, a12 = 0.f;
        float a20 = 0.f, a21 = 0.f, a22 = 0.f;
        uint4 xa0, xa1, xa2, wa0, wa1, wa2;
        uint4 xb0, xb1, xb2, wb0, wb1, wb2;

#define LOADIT(X0, X1, X2, W0, W1, W2, IT) do {                              \
        const int gi4 = ((IT) * 64 + lane) * 4;                              \
        X0 = *reinterpret_cast<const uint4*>(&xh[0][gi4]);                   \
        X1 = *reinterpret_cast<const uint4*>(&xh[1][gi4]);                   \
        X2 = *reinterpret_cast<const uint4*>(&xh[2][gi4]);                   \
        W0 = *reinterpret_cast<const uint4*>(Wp0 + gi4);                     \
        W1 = *reinterpret_cast<const uint4*>(Wp1 + gi4);                     \
        W2 = *reinterpret_cast<const uint4*>(Wp2 + gi4);                     \
    } while (0)
#define DOT4(A, WV, XV) do {                                                 \
        A = dot2(WV.x, XV.x, A); A = dot2(WV.y, XV.y, A);                    \
        A = dot2(WV.z, XV.z, A); A = dot2(WV.w, XV.w, A);                    \
    } while (0)
#define CONSUME(X0, X1, X2, W0, W1, W2) do {                                 \
        DOT4(a00, W0, X0); DOT4(a01, W0, X1); DOT4(a02, W0, X2);             \
        DOT4(a10, W1, X0); DOT4(a11, W1, X1); DOT4(a12, W1, X2);             \
        DOT4(a20, W2, X0); DOT4(a21, W2, X1); DOT4(a22, W2, X2);             \
    } while (0)

        LOADIT(xa0, xa1, xa2, wa0, wa1, wa2, 0);
#pragma unroll 1
        for (int it2 = 0; it2 < 7; ++it2) {
            LOADIT(xb0, xb1, xb2, wb0, wb1, wb2, 2 * it2 + 1);
            CONSUME(xa0, xa1, xa2, wa0, wa1, wa2);
            LOADIT(xa0, xa1, xa2, wa0, wa1, wa2, 2 * it2 + 2);
            CONSUME(xb0, xb1, xb2, wb0, wb1, wb2);
            // per-iter pin: loads of BOTH stages issue before the dot2 block
            SGB(M_VMEMRD, 3);
            SGB(M_DSRD, 3);
            SGB(M_VMEMRD, 3);
            SGB(M_DSRD, 3);
            SGB(M_VALU, 96);
        }
        LOADIT(xb0, xb1, xb2, wb0, wb1, wb2, 15);
        CONSUME(xa0, xa1, xa2, wa0, wa1, wa2);
        CONSUME(xb0, xb1, xb2, wb0, wb1, wb2);
#undef LOADIT
#undef DOT4
#undef CONSUME

        // 9 interleaved butterfly chains
#pragma unroll
        for (int m = 1; m < 64; m <<= 1) {
            a00 += __shfl_xor(a00, m, 64); a01 += __shfl_xor(a01, m, 64);
            a02 += __shfl_xor(a02, m, 64); a10 += __shfl_xor(a10, m, 64);
            a11 += __shfl_xor(a11, m, 64); a12 += __shfl_xor(a12, m, 64);
            a20 += __shfl_xor(a20, m, 64); a21 += __shfl_xor(a21, m, 64);
            a22 += __shfl_xor(a22, m, 64);
        }
        if (lane == 0) {
            lg[0][r0] = a00;     lg[1][r0] = a01;     lg[2][r0] = a02;
            lg[0][r0 + 1] = a10; lg[1][r0 + 1] = a11; lg[2][r0 + 1] = a12;
            lg[0][r0 + 2] = a20; lg[1][r0 + 2] = a21; lg[2][r0 + 2] = a22;
        }
    }
    __syncthreads();

    // ---- weights: scalar per-token (3 lanes), sinkhorn fully in regs ----
    if (t < TOKS && gt0 + t < NTOK) {
        float ss = ssred[t][0] + ssred[t][1] + ssred[t][2] + ssred[t][3]
                 + ssred[t][4] + ssred[t][5] + ssred[t][6] + ssred[t][7];
        float rms = rsqrtf(ss * (1.f / 8192.f) + EPS);
        float s0 = scale[0], s1 = scale[1], s2 = scale[2];
        float l[24];
#pragma unroll
        for (int i = 0; i < 24; ++i) l[i] = lg[t][i];
#pragma unroll
        for (int k = 0; k < 4; ++k) {
            float z0 = l[k] * rms * s0 + base[k];
            wts[t][k] = frcp(1.f + __expf(-z0)) + EPS;
            float z1 = l[4 + k] * rms * s1 + base[4 + k];
            wts[t][4 + k] = 2.f * frcp(1.f + __expf(-z1));
        }
        float p[16];
#pragma unroll
        for (int h = 0; h < 4; ++h) {
            float c0 = l[8 + h * 4 + 0] * rms * s2 + base[8 + h * 4 + 0];
            float c1 = l[8 + h * 4 + 1] * rms * s2 + base[8 + h * 4 + 1];
            float c2 = l[8 + h * 4 + 2] * rms * s2 + base[8 + h * 4 + 2];
            float c3 = l[8 + h * 4 + 3] * rms * s2 + base[8 + h * 4 + 3];
            float mx = fmaxf(fmaxf(c0, c1), fmaxf(c2, c3));
            float e0 = __expf(c0 - mx), e1 = __expf(c1 - mx);
            float e2 = __expf(c2 - mx), e3 = __expf(c3 - mx);
            float inv = frcp(e0 + e1 + e2 + e3);
            p[h * 4 + 0] = e0 * inv + EPS; p[h * 4 + 1] = e1 * inv + EPS;
            p[h * 4 + 2] = e2 * inv + EPS; p[h * 4 + 3] = e3 * inv + EPS;
        }
#pragma unroll
        for (int k = 0; k < 4; ++k) {
            float inv = frcp(p[k] + p[4 + k] + p[8 + k] + p[12 + k] + EPS);
            p[k] *= inv; p[4 + k] *= inv; p[8 + k] *= inv; p[12 + k] *= inv;
        }
#pragma unroll 1
        for (int itn = 0; itn < 19; ++itn) {
#pragma unroll
            for (int h = 0; h < 4; ++h) {
                float inv = frcp(p[h * 4] + p[h * 4 + 1] + p[h * 4 + 2] + p[h * 4 + 3] + EPS);
                p[h * 4] *= inv; p[h * 4 + 1] *= inv; p[h * 4 + 2] *= inv; p[h * 4 + 3] *= inv;
            }
#pragma unroll
            for (int k = 0; k < 4; ++k) {
                float inv = frcp(p[k] + p[4 + k] + p[8 + k] + p[12 + k] + EPS);
                p[k] *= inv; p[4 + k] *= inv; p[8 + k] *= inv; p[12 + k] *= inv;
            }
        }
#pragma unroll
        for (int i = 0; i < 16; ++i) wts[t][8 + i] = p[i];
    }
    __syncthreads();

    // ---- phase B: per token, all 512 threads, out already in regs ----
#define PHASEB(TT, OV) do {                                                  \
    if (gt0 + TT < NTOK) {                                                   \
        float pre[4], post[4], cmb[4][4];                                    \
        _Pragma("unroll")                                                    \
        for (int k = 0; k < 4; ++k) { pre[k] = wts[TT][k]; post[k] = wts[TT][4 + k]; } \
        _Pragma("unroll")                                                    \
        for (int h = 0; h < 4; ++h)                                          \
            _Pragma("unroll")                                                \
            for (int k = 0; k < 4; ++k) cmb[h][k] = wts[TT][8 + h * 4 + k];  \
        const int d = t * 4;                                                 \
        float xk[4][4];                                                      \
        _Pragma("unroll")                                                    \
        for (int k = 0; k < 4; ++k) {                                        \
            uint2 pq = *reinterpret_cast<const uint2*>(&xh[TT][k * 1024 + t * 2]); \
            h2 h0 = __builtin_bit_cast(h2, pq.x), h1 = __builtin_bit_cast(h2, pq.y); \
            xk[k][0] = (float)h0.x; xk[k][1] = (float)h0.y;                  \
            xk[k][2] = (float)h1.x; xk[k][3] = (float)h1.y;                  \
        }                                                                    \
        float* yb = y + (gt0 + TT) * KD;                                     \
        float* cb = coll + (gt0 + TT) * D_;                                  \
        float cv[4], yv[4];                                                  \
        _Pragma("unroll")                                                    \
        for (int e = 0; e < 4; ++e)                                          \
            cv[e] = pre[0] * xk[0][e] + pre[1] * xk[1][e]                    \
                  + pre[2] * xk[2][e] + pre[3] * xk[3][e];                   \
        *reinterpret_cast<float4*>(cb + d) = make_float4(cv[0], cv[1], cv[2], cv[3]); \
        const float oe[4] = {OV.x, OV.y, OV.z, OV.w};                        \
        _Pragma("unroll")                                                    \
        for (int h = 0; h < 4; ++h) {                                        \
            _Pragma("unroll")                                                \
            for (int e = 0; e < 4; ++e)                                      \
                yv[e] = post[h] * oe[e] + cmb[h][0] * xk[0][e] + cmb[h][1] * xk[1][e] \
                      + cmb[h][2] * xk[2][e] + cmb[h][3] * xk[3][e];         \
            *reinterpret_cast<float4*>(yb + h * D_ + d) =                    \
                make_float4(yv[0], yv[1], yv[2], yv[3]);                     \
        }                                                                    \
    } } while (0)

    PHASEB(0, ov0);
    PHASEB(1, ov1);
    PHASEB(2, ov2);
#undef PHASEB
}

extern "C" void kernel_launch(void* const* d_in, const int* in_sizes, int n_in,
                              void* d_out, int out_size, void* d_ws, size_t ws_size,
                              hipStream_t stream) {
    const float* x     = (const float*)d_in[0];
    const float* outp  = (const float*)d_in[1];
    const float* W     = (const float*)d_in[2];
    const float* scale = (const float*)d_in[3];
    const float* base  = (const float*)d_in[4];
    float* y    = (float*)d_out;
    float* coll = y + (size_t)NTOK * KD;   // 67108864

    unsigned int* Wh = (unsigned int*)d_ws;     // 384 KB f16 (ws is larger)
    conv_w_kernel<<<NOUT * KD / 8 / 256, 256, 0, stream>>>(W, Wh);
    hypermix_kernel<<<NBLK, TPB, 0, stream>>>(x, outp, Wh, scale, base, y, coll);
}